// Round 11
// baseline (395.395 us; speedup 1.0000x reference)
//
#include <hip/hip_runtime.h>
#include <hip/hip_bf16.h>

typedef __hip_bfloat16 bf16;
typedef short  sv4 __attribute__((ext_vector_type(4)));
typedef short  sv8 __attribute__((ext_vector_type(8)));
typedef float  f32x4 __attribute__((ext_vector_type(4)));
typedef float  fv2  __attribute__((ext_vector_type(2)));
typedef unsigned int uv4 __attribute__((ext_vector_type(4)));

#define CH      64
#define DWC     128
#define SDIM    512
#define SPATIAL (64*64*64)     // 262144
#define NB      2
#define NVOX    (NB*SPATIAL)

// padded h layout: per (b,g): [d][hy][65 chunks], chunk 0 of each row = zero pad
#define ROWS      65
#define PLANE_CH  (64*ROWS)          // 4160 chunks per d-plane
#define BG_CH     (64*PLANE_CH)      // 266240 chunks per (b,g)
#define HPAD_CHUNKS ((size_t)32*BG_CH + 16)
#define HPAD_BYTES  (HPAD_CHUNKS*16)

// f32 workspace offsets (floats), area starts after h + a
#define OFF_SMOD   0
#define OFF_POOLED 256
#define OFF_PB1    512     // b1p [128]
#define OFF_PB4    768     // b4p [128]
#define OFF_PB35   1024    // (b3, beta, gamma, b5) quads [64]
#define OFF_MODWT  1536    // [27][128]
#define OFF_U16    5120    // start of bf16 weight area (in floats)
// sv8-fragment tables, short offsets from (short*)(wsf + OFF_U16):
#define U16_W1F 0          // [8 kf][128 m][8]
#define U16_W3F 8192       // [2 b][16 kf][64 m][8]  (gate-folded)
#define U16_W4F 24576      // [8 kf][128 m][8]
#define U16_W5F 32768      // [16 kf][64 m][8]

#define A_BYTES ((size_t)NB * DWC * SPATIAL * 2)

__device__ __forceinline__ float b2f(short u) {
    return __uint_as_float(((unsigned)(unsigned short)u) << 16);
}
__device__ __forceinline__ short f2bs(float f) {
    __hip_bfloat16 h = __float2bfloat16(f);
    return __builtin_bit_cast(short, h);
}
// tanh-form gelu: x * sigmoid(1.5957691*x*(1+0.044715*x^2)); |err| < ~1e-3
__device__ __forceinline__ float gelu_f(float x) {
    float x2 = x * x;
    float z  = x * fmaf(x2, 0.07135481627f, 1.5957691216f);
    float e  = exp2f(-1.4426950409f * z);
    return x * __builtin_amdgcn_rcpf(1.f + e);
}

// ---------------- K0: prep (8 blocks) ------------------------------------
__global__ void prep_kernel(const float* __restrict__ style,
                            const float* __restrict__ w1, const float* __restrict__ b1,
                            const float* __restrict__ mod_w,
                            const float* __restrict__ style_w, const float* __restrict__ style_b,
                            const float* __restrict__ b3,
                            const float* __restrict__ w4, const float* __restrict__ b4,
                            const float* __restrict__ w5, const float* __restrict__ b5,
                            const float* __restrict__ ln1w, const float* __restrict__ ln1b,
                            const float* __restrict__ ln2w, const float* __restrict__ ln2b,
                            const float* __restrict__ beta, const float* __restrict__ gamma,
                            float* __restrict__ wsf, sv8* __restrict__ h) {
    int t = threadIdx.x;   // 256 threads, 8 blocks
    int B = blockIdx.x;
    short* w16 = (short*)(wsf + OFF_U16);

    if (B == 0) {
        if (t < 16) {
            const sv8 zz = {0,0,0,0,0,0,0,0};
            h[(size_t)32*BG_CH + t] = zz;
        }
        if (t < DWC) {
            float bb1 = b1[t], bb4 = b4[t];
            for (int c = 0; c < CH; ++c) {
                bb1 = fmaf(w1[t*CH + c], ln1b[c], bb1);
                bb4 = fmaf(w4[t*CH + c], ln2b[c], bb4);
            }
            wsf[OFF_PB1 + t] = bb1;
            wsf[OFF_PB4 + t] = bb4;
        }
        if (t < CH) {
            wsf[OFF_PB35 + 4*t + 0] = b3[t];
            wsf[OFF_PB35 + 4*t + 1] = beta[t];
            wsf[OFF_PB35 + 4*t + 2] = gamma[t];
            wsf[OFF_PB35 + 4*t + 3] = b5[t];
        }
        for (int idx = t; idx < 27*DWC; idx += 256) {   // mod_w transpose [27][128]
            int k = idx >> 7, c = idx & 127;
            wsf[OFF_MODWT + idx] = mod_w[c*27 + k];
        }
    }
    {   // s*demod: 32 outputs per block, 8 threads per output
        int o   = B*32 + (t >> 3);
        int sub = t & 7;
        int b = o >> 7, ch = o & 127;
        const float4* s4 = (const float4*)(style + b*SDIM) + sub*16;
        const float4* wv = (const float4*)(style_w + ch*SDIM) + sub*16;
        float s0=0.f, s1=0.f, s2=0.f, s3=0.f;
        #pragma unroll
        for (int i = 0; i < 16; ++i) {
            float4 a_ = s4[i], b_ = wv[i];
            s0 = fmaf(a_.x, b_.x, s0); s1 = fmaf(a_.y, b_.y, s1);
            s2 = fmaf(a_.z, b_.z, s2); s3 = fmaf(a_.w, b_.w, s3);
        }
        float ps = (s0 + s1) + (s2 + s3);
        ps += __shfl_xor(ps, 1); ps += __shfl_xor(ps, 2); ps += __shfl_xor(ps, 4);
        if (sub == 0) {
            float s = style_b[ch] + ps;
            float k2 = 0.f;
            for (int j = 0; j < 27; ++j) { float w = mod_w[ch*27 + j]; k2 = fmaf(w, w, k2); }
            wsf[OFF_SMOD + o]   = s * rsqrtf(fmaf(k2, s*s, 1e-8f));
            wsf[OFF_POOLED + o] = 0.f;
        }
    }
    for (int idx = B*1024 + t; idx < B*1024 + 1024; idx += 256) {  // W1F / W4F
        int m = idx >> 6, k = idx & 63;
        int dst = (((k >> 3)*DWC + m) << 3) + (k & 7);
        w16[U16_W1F + dst] = f2bs(w1[idx] * ln1w[k]);
        w16[U16_W4F + dst] = f2bs(w4[idx] * ln2w[k]);
    }
    for (int idx = B*1024 + t; idx < B*1024 + 1024; idx += 256) {  // W5F
        int m = idx >> 7, k = idx & 127;
        w16[U16_W5F + (((k >> 3)*CH + m) << 3) + (k & 7)] = f2bs(w5[idx]);
    }
}

// ---------------- K1: LN1 + pw1 (MFMA) -> h padded layout ----------------
// One 16-voxel job per wave; W1F staged in LDS (round-8 tail recipe).
__global__ __launch_bounds__(256) void lnpw1_kernel(const float* __restrict__ inp,
                                                    const float* __restrict__ wsf,
                                                    sv8* __restrict__ h) {
    __shared__ sv8  w1s[1024];            // 16 KB
    __shared__ short ht[4*2176];          // 17 KB transpose
    int tid  = threadIdx.x;
    int blk  = blockIdx.x;
    int wid  = tid >> 6;
    int lane = tid & 63;
    int col  = lane & 15, grp = lane >> 4;
    int b    = blk >> 12;
    int row  = blk & 4095;                 // row within batch (d*64+hy)
    int vx   = (row << 6) + (wid << 4) + col;

    const float* b1p = wsf + OFF_PB1;
    short* hw = ht + wid*2176;

    // ---- issue inp loads first, then stage W1F behind them ----
    const float* xp = inp + (size_t)b * CH * SPATIAL + vx;
    float xv[16];
    #pragma unroll
    for (int e = 0; e < 16; ++e) {
        int k = ((e >> 3) << 5) + (grp << 3) + (e & 7);
        xv[e] = xp[(size_t)k * SPATIAL];
    }
    {
        const sv8* src = (const sv8*)((const short*)(wsf + OFF_U16) + U16_W1F);
        #pragma unroll
        for (int i = 0; i < 4; ++i) w1s[i*256 + tid] = src[i*256 + tid];
    }
    __syncthreads();

    float sum = 0.f, ssq = 0.f;
    #pragma unroll
    for (int e = 0; e < 16; ++e) { sum += xv[e]; ssq = fmaf(xv[e], xv[e], ssq); }
    sum += __shfl_xor(sum, 16); sum += __shfl_xor(sum, 32);
    ssq += __shfl_xor(ssq, 16); ssq += __shfl_xor(ssq, 32);
    float m   = sum * (1.f/64.f);
    float var = fmaxf((ssq - 64.f*m*m) * (1.f/63.f), 0.f);
    float inv = 1.f / (sqrtf(var) + 1e-6f);

    sv8 xb0, xb1;
    #pragma unroll
    for (int i = 0; i < 8; ++i) {
        xb0[i] = f2bs((xv[i]     - m) * inv);
        xb1[i] = f2bs((xv[8 + i] - m) * inv);
    }

    __builtin_amdgcn_s_setprio(1);
    f32x4 acc[8] = {};
    #pragma unroll
    for (int mt = 0; mt < 8; ++mt) {
        acc[mt] = __builtin_amdgcn_mfma_f32_16x16x32_bf16(w1s[(grp    )*DWC + mt*16 + col], xb0, acc[mt], 0, 0, 0);
        acc[mt] = __builtin_amdgcn_mfma_f32_16x16x32_bf16(w1s[(grp + 4)*DWC + mt*16 + col], xb1, acc[mt], 0, 0, 0);
    }
    __builtin_amdgcn_s_setprio(0);

    // epilogue + transpose to [v][8ch] chunks
    #pragma unroll
    for (int mt = 0; mt < 8; ++mt) {
        sv4 p;
        #pragma unroll
        for (int r = 0; r < 4; ++r) {
            int f = mt*16 + 4*grp + r;
            p[r] = f2bs(acc[mt][r] + b1p[f]);
        }
        *(sv4*)(hw + col*136 + mt*16 + 4*grp) = p;
    }
    #pragma unroll
    for (int gq = 0; gq < 4; ++gq) {
        int g = gq*4 + grp;
        sv8 vrow = *(const sv8*)(hw + col*136 + g*8);
        size_t base = (size_t)(b*16 + g) * BG_CH + row*ROWS;
        h[base + 1 + (wid << 4) + col] = vrow;
        if (wid == 0 && col == 0) {       // zero this row's pad chunk
            const sv8 zz = {0,0,0,0,0,0,0,0};
            h[base] = zz;
        }
    }
}

// ---------------- K2: depthwise 3x3x3 + mod + GELU -> a, pooled ---------
// packed-f32 (fv2) math: v_pk_fma_f32 does 2 FMAs per issue slot.
__global__ __launch_bounds__(256) void conv_kernel(const sv8* __restrict__ h,
                                                   const float* __restrict__ mod_b,
                                                   const float* __restrict__ wsf,
                                                   sv8* __restrict__ a,
                                                   float* __restrict__ pooled) {
    __shared__ float part[4][8];
    int tid = threadIdx.x;
    int w   = tid & 63;
    int dq  = tid >> 6;
    int hy  = blockIdx.x & 63;
    int bg  = blockIdx.x >> 6;
    int g   = bg & 15;
    int b   = bg >> 4;

    const sv8* hP  = h + (size_t)bg * BG_CH;
    sv8*      adst = a + (size_t)bg * SPATIAL;
    const float* mwt = wsf + OFF_MODWT + g*8;
    const float* smp = wsf + OFF_SMOD + b*DWC + g*8;
    const float* mbp = mod_b + g*8;

    bool r0ok = (hy > 0), r2ok = (hy < 63);
    int d0 = dq << 4;

    fv2 an[4] = {}, am[4] = {}, ao[4] = {};
    fv2 psum[4] = {};

    #pragma unroll 1
    for (int i = 0; i < 18; ++i) {
        int dd = d0 - 1 + i;
        fv2 f[9][4];
        if ((unsigned)dd < 64u) {
            const sv8* p = hP + dd*PLANE_CH + hy*ROWS + 1 + w;
            sv8 cv[9];
            const sv8 zz = {0,0,0,0,0,0,0,0};
            if (r0ok) { cv[0] = p[-ROWS-1]; cv[1] = p[-ROWS]; cv[2] = p[-ROWS+1]; }
            else      { cv[0] = zz; cv[1] = zz; cv[2] = zz; }
            cv[3] = p[-1]; cv[4] = p[0]; cv[5] = p[1];
            if (r2ok) { cv[6] = p[ROWS-1]; cv[7] = p[ROWS]; cv[8] = p[ROWS+1]; }
            else      { cv[6] = zz; cv[7] = zz; cv[8] = zz; }
            #pragma unroll
            for (int r = 0; r < 9; ++r) {
                uv4 u = __builtin_bit_cast(uv4, cv[r]);
                #pragma unroll
                for (int c4 = 0; c4 < 4; ++c4) {
                    fv2 fr;
                    fr.x = __uint_as_float(u[c4] << 16);
                    fr.y = __uint_as_float(u[c4] & 0xFFFF0000u);
                    f[r][c4] = fr;
                }
            }
        } else {
            #pragma unroll
            for (int r = 0; r < 9; ++r)
                #pragma unroll
                for (int c4 = 0; c4 < 4; ++c4) f[r][c4] = (fv2)(0.f);
        }

        if (i >= 2) {
            #pragma unroll
            for (int r = 0; r < 9; ++r) {
                const fv2* wr = (const fv2*)(mwt + (18 + r)*DWC);
                #pragma unroll
                for (int c4 = 0; c4 < 4; ++c4) ao[c4] = wr[c4]*f[r][c4] + ao[c4];
            }
            int o = d0 + i - 2;
            sv8 ov;
            #pragma unroll
            for (int c4 = 0; c4 < 4; ++c4) {
                float v0 = gelu_f(fmaf(ao[c4].x, smp[2*c4],     mbp[2*c4]));
                float v1 = gelu_f(fmaf(ao[c4].y, smp[2*c4 + 1], mbp[2*c4 + 1]));
                psum[c4].x += v0; psum[c4].y += v1;
                ov[2*c4]     = f2bs(v0);
                ov[2*c4 + 1] = f2bs(v1);
            }
            adst[o*4096 + hy*64 + w] = ov;
        }
        if (i >= 1 && i <= 16) {
            #pragma unroll
            for (int r = 0; r < 9; ++r) {
                const fv2* wr = (const fv2*)(mwt + (9 + r)*DWC);
                #pragma unroll
                for (int c4 = 0; c4 < 4; ++c4) am[c4] = wr[c4]*f[r][c4] + am[c4];
            }
        }
        if (i <= 15) {
            #pragma unroll
            for (int c4 = 0; c4 < 4; ++c4) an[c4] = (fv2)(0.f);
            #pragma unroll
            for (int r = 0; r < 9; ++r) {
                const fv2* wr = (const fv2*)(mwt + r*DWC);
                #pragma unroll
                for (int c4 = 0; c4 < 4; ++c4) an[c4] = wr[c4]*f[r][c4] + an[c4];
            }
        }
        #pragma unroll
        for (int c4 = 0; c4 < 4; ++c4) { ao[c4] = am[c4]; am[c4] = an[c4]; }
    }

    #pragma unroll
    for (int c = 0; c < 8; ++c) {
        float s = (c & 1) ? psum[c >> 1].y : psum[c >> 1].x;
        #pragma unroll
        for (int off = 32; off > 0; off >>= 1) s += __shfl_xor(s, off);
        if ((tid & 63) == 0) part[dq][c] = s;
    }
    __syncthreads();
    if (tid < 8)
        atomicAdd(&pooled[b*DWC + g*8 + tid],
                  part[0][tid] + part[1][tid] + part[2][tid] + part[3][tid]);
}

// ---------------- K3: SCA gate + fold into W3F (bf16 frags) -------------
__global__ void gate_kernel(const float* __restrict__ sca_w,
                            const float* __restrict__ sca_b,
                            const float* __restrict__ w3,
                            float* __restrict__ wsf) {
    __shared__ float gsh[256];
    int t = threadIdx.x;                  // 256, 8 blocks
    int b = t >> 7, o = t & 127;
    const float invS = 1.f / (float)SPATIAL;
    float gval = sca_b[o];
    for (int i = 0; i < DWC; ++i)
        gval = fmaf(sca_w[o*DWC + i], wsf[OFF_POOLED + b*DWC + i] * invS, gval);
    gsh[t] = gval;
    __syncthreads();
    int e = blockIdx.x * 256 + t;         // 0..2047 sv8 frags
    int bb = e >> 10, kf = (e >> 6) & 15, m = e & 63;
    sv8 frag;
    #pragma unroll
    for (int i = 0; i < 8; ++i) {
        int k = kf*8 + i;
        frag[i] = f2bs(w3[m*DWC + k] * gsh[bb*DWC + k]);
    }
    sv8* w3f = (sv8*)((short*)(wsf + OFF_U16) + U16_W3F);
    w3f[e] = frag;
}

// ---------------- K4: pw3 + residual + LN2 + pw4 + GELU + pw5 (MFMA) ----
// Round-8 structure: 1 job/wave, 8192 blocks, W3 staged in LDS (separate
// buffers, single barrier) + setprio around MFMA clusters.
__global__ __launch_bounds__(256) void tail_kernel(const float* __restrict__ inp,
                                                   const sv8* __restrict__ a,
                                                   const float* __restrict__ wsf,
                                                   float* __restrict__ out) {
    __shared__ sv8  w3s[1024];            // 16 KB
    __shared__ short yt[4][2176];         // 17 KB transpose
    int tid  = threadIdx.x;
    int wid  = tid >> 6;
    int lane = tid & 63;
    int col  = lane & 15, grp = lane >> 4;
    int blk  = blockIdx.x;
    int b    = blk >> 12;
    int vx   = ((blk & 4095) << 6) + (wid << 4) + col;

    const short* w16 = (const short*)(wsf + OFF_U16);
    const sv8* W4 = (const sv8*)(w16 + U16_W4F);
    const sv8* W5 = (const sv8*)(w16 + U16_W5F);
    const float*  b4p  = wsf + OFF_PB4;
    const float4* pb35 = (const float4*)(wsf + OFF_PB35);
    short* yw = &yt[wid][0];

    // ---- issue HBM loads first (a-chunks + inp), then stage W3 ----
    sv8 bq[4];
    #pragma unroll
    for (int ks = 0; ks < 4; ++ks)
        bq[ks] = a[(size_t)(b*16 + ks*4 + grp) * SPATIAL + vx];
    float xin[16];
    #pragma unroll
    for (int j = 0; j < 16; ++j) {
        int c = (j >> 2)*16 + 4*grp + (j & 3);
        xin[j] = inp[((size_t)(b*CH + c)) * SPATIAL + vx];
    }
    {
        const sv8* src = (const sv8*)(w16 + U16_W3F) + (size_t)b * 1024;
        #pragma unroll
        for (int i = 0; i < 4; ++i) w3s[i*256 + tid] = src[i*256 + tid];
    }
    __syncthreads();

    // ---- pw3 (W3 from LDS) ----
    __builtin_amdgcn_s_setprio(1);
    f32x4 acc3[4] = {};
    #pragma unroll
    for (int mt = 0; mt < 4; ++mt)
        #pragma unroll
        for (int ks = 0; ks < 4; ++ks)
            acc3[mt] = __builtin_amdgcn_mfma_f32_16x16x32_bf16(
                w3s[(ks*4 + grp)*64 + mt*16 + col], bq[ks], acc3[mt], 0, 0, 0);
    __builtin_amdgcn_s_setprio(0);

    // ---- residual + LN2 stats ----
    float y[16];
    float sum = 0.f, ssq = 0.f;
    #pragma unroll
    for (int mt = 0; mt < 4; ++mt)
        #pragma unroll
        for (int r = 0; r < 4; ++r) {
            int c = mt*16 + 4*grp + r;
            float4 pb = pb35[c];
            float tt = acc3[mt][r] + pb.x;
            float yv = fmaf(tt, pb.y, xin[mt*4 + r]);
            y[mt*4 + r] = yv; sum += yv; ssq = fmaf(yv, yv, ssq);
        }
    sum += __shfl_xor(sum, 16); sum += __shfl_xor(sum, 32);
    ssq += __shfl_xor(ssq, 16); ssq += __shfl_xor(ssq, 32);
    float m2   = sum * (1.f/64.f);
    float var2 = fmaxf((ssq - 64.f*m2*m2) * (1.f/63.f), 0.f);
    float inv2 = 1.f / (sqrtf(var2) + 1e-6f);

    // ---- normalized y -> bf16 B-frags via LDS transpose ----
    #pragma unroll
    for (int mt = 0; mt < 4; ++mt) {
        sv4 p;
        #pragma unroll
        for (int r = 0; r < 4; ++r)
            p[r] = f2bs((y[mt*4 + r] - m2) * inv2);
        *(sv4*)(yw + col*136 + mt*16 + 4*grp) = p;
    }
    sv8 by0 = *(const sv8*)(yw + col*136 + grp*8);
    sv8 by1 = *(const sv8*)(yw + col*136 + grp*8 + 32);

    // ---- pw4 ----
    __builtin_amdgcn_s_setprio(1);
    f32x4 acc4[8] = {};
    #pragma unroll
    for (int mt = 0; mt < 8; ++mt) {
        acc4[mt] = __builtin_amdgcn_mfma_f32_16x16x32_bf16(W4[(grp    )*DWC + mt*16 + col], by0, acc4[mt], 0, 0, 0);
        acc4[mt] = __builtin_amdgcn_mfma_f32_16x16x32_bf16(W4[(grp + 4)*DWC + mt*16 + col], by1, acc4[mt], 0, 0, 0);
    }
    __builtin_amdgcn_s_setprio(0);

    // ---- gelu -> bf16 B-frags ----
    #pragma unroll
    for (int mt = 0; mt < 8; ++mt) {
        sv4 p;
        #pragma unroll
        for (int r = 0; r < 4; ++r) {
            int f = mt*16 + 4*grp + r;
            p[r] = f2bs(gelu_f(acc4[mt][r] + b4p[f]));
        }
        *(sv4*)(yw + col*136 + mt*16 + 4*grp) = p;
    }
    sv8 bg[4];
    #pragma unroll
    for (int ks = 0; ks < 4; ++ks)
        bg[ks] = *(const sv8*)(yw + col*136 + grp*8 + ks*32);

    // ---- pw5 ----
    __builtin_amdgcn_s_setprio(1);
    f32x4 acc5[4] = {};
    #pragma unroll
    for (int mt = 0; mt < 4; ++mt)
        #pragma unroll
        for (int ks = 0; ks < 4; ++ks)
            acc5[mt] = __builtin_amdgcn_mfma_f32_16x16x32_bf16(
                W5[(ks*4 + grp)*64 + mt*16 + col], bg[ks], acc5[mt], 0, 0, 0);
    __builtin_amdgcn_s_setprio(0);

    #pragma unroll
    for (int mt = 0; mt < 4; ++mt)
        #pragma unroll
        for (int r = 0; r < 4; ++r) {
            int c = mt*16 + 4*grp + r;
            float4 pb = pb35[c];
            float o = fmaf(acc5[mt][r] + pb.w, pb.z, y[mt*4 + r]);
            out[((size_t)(b*CH + c)) * SPATIAL + vx] = o;
        }
}

// ---------------- host launcher -----------------------------------------
extern "C" void kernel_launch(void* const* d_in, const int* in_sizes, int n_in,
                              void* d_out, int out_size, void* d_ws, size_t ws_size,
                              hipStream_t stream) {
    const float* inp     = (const float*)d_in[0];
    const float* style   = (const float*)d_in[1];
    const float* w1      = (const float*)d_in[2];
    const float* b1      = (const float*)d_in[3];
    const float* mod_w   = (const float*)d_in[4];
    const float* mod_b   = (const float*)d_in[5];
    const float* style_w = (const float*)d_in[6];
    const float* style_b = (const float*)d_in[7];
    const float* sca_w   = (const float*)d_in[8];
    const float* sca_b   = (const float*)d_in[9];
    const float* w3      = (const float*)d_in[10];
    const float* b3      = (const float*)d_in[11];
    const float* w4      = (const float*)d_in[12];
    const float* b4      = (const float*)d_in[13];
    const float* w5      = (const float*)d_in[14];
    const float* b5      = (const float*)d_in[15];
    const float* ln1w    = (const float*)d_in[16];
    const float* ln1b    = (const float*)d_in[17];
    const float* ln2w    = (const float*)d_in[18];
    const float* ln2b    = (const float*)d_in[19];
    const float* beta    = (const float*)d_in[20];
    const float* gamma   = (const float*)d_in[21];

    sv8*   h   = (sv8*)d_ws;
    sv8*   a   = (sv8*)((char*)d_ws + HPAD_BYTES);
    float* wsf = (float*)((char*)d_ws + HPAD_BYTES + A_BYTES);
    float* out = (float*)d_out;

    prep_kernel<<<8, 256, 0, stream>>>(style, w1, b1, mod_w, style_w, style_b,
                                       b3, w4, b4, w5, b5,
                                       ln1w, ln1b, ln2w, ln2b, beta, gamma, wsf, h);
    lnpw1_kernel<<<8192, 256, 0, stream>>>(inp, wsf, h);
    conv_kernel<<<2048, 256, 0, stream>>>(h, mod_b, wsf, a, wsf + OFF_POOLED);
    gate_kernel<<<8, 256, 0, stream>>>(sca_w, sca_b, w3, wsf);
    tail_kernel<<<8192, 256, 0, stream>>>(inp, a, wsf, out);
}

// Round 12
// 330.510 us; speedup vs baseline: 1.1963x; 1.1963x over previous
//
#include <hip/hip_runtime.h>
#include <hip/hip_bf16.h>

typedef __hip_bfloat16 bf16;
typedef short  sv4 __attribute__((ext_vector_type(4)));
typedef short  sv8 __attribute__((ext_vector_type(8)));
typedef float  f32x4 __attribute__((ext_vector_type(4)));
typedef float  fv2  __attribute__((ext_vector_type(2)));
typedef unsigned int uv4 __attribute__((ext_vector_type(4)));

#define CH      64
#define DWC     128
#define SDIM    512
#define SPATIAL (64*64*64)     // 262144
#define NB      2
#define NVOX    (NB*SPATIAL)

// padded h layout: per (b,g): [d][hy][65 chunks], chunk 0 of each row = zero pad
#define ROWS      65
#define PLANE_CH  (64*ROWS)          // 4160 chunks per d-plane
#define BG_CH     (64*PLANE_CH)      // 266240 chunks per (b,g)
#define HPAD_CHUNKS ((size_t)32*BG_CH + 16)
#define HPAD_BYTES  (HPAD_CHUNKS*16)

// f32 workspace offsets (floats), area starts after h + a
#define OFF_SMOD   0
#define OFF_POOLED 256
#define OFF_PB1    512     // b1p [128]
#define OFF_PB4    768     // b4p [128]
#define OFF_PB35   1024    // (b3, beta, gamma, b5) quads [64]
#define OFF_MODWT  1536    // [27][128]
#define OFF_U16    5120    // start of bf16 weight area (in floats)
// sv8-fragment tables, short offsets from (short*)(wsf + OFF_U16):
#define U16_W1F 0          // [8 kf][128 m][8]
#define U16_W3F 8192       // [2 b][16 kf][64 m][8]  (gate-folded)
#define U16_W4F 24576      // [8 kf][128 m][8]
#define U16_W5F 32768      // [16 kf][64 m][8]

#define A_BYTES ((size_t)NB * DWC * SPATIAL * 2)

__device__ __forceinline__ float b2f(short u) {
    return __uint_as_float(((unsigned)(unsigned short)u) << 16);
}
__device__ __forceinline__ short f2bs(float f) {
    __hip_bfloat16 h = __float2bfloat16(f);
    return __builtin_bit_cast(short, h);
}
// tanh-form gelu: x * sigmoid(1.5957691*x*(1+0.044715*x^2)); |err| < ~1e-3
__device__ __forceinline__ float gelu_f(float x) {
    float x2 = x * x;
    float z  = x * fmaf(x2, 0.07135481627f, 1.5957691216f);
    float e  = exp2f(-1.4426950409f * z);
    return x * __builtin_amdgcn_rcpf(1.f + e);
}

// ---------------- K0: prep (8 blocks) ------------------------------------
__global__ void prep_kernel(const float* __restrict__ style,
                            const float* __restrict__ w1, const float* __restrict__ b1,
                            const float* __restrict__ mod_w,
                            const float* __restrict__ style_w, const float* __restrict__ style_b,
                            const float* __restrict__ b3,
                            const float* __restrict__ w4, const float* __restrict__ b4,
                            const float* __restrict__ w5, const float* __restrict__ b5,
                            const float* __restrict__ ln1w, const float* __restrict__ ln1b,
                            const float* __restrict__ ln2w, const float* __restrict__ ln2b,
                            const float* __restrict__ beta, const float* __restrict__ gamma,
                            float* __restrict__ wsf, sv8* __restrict__ h) {
    int t = threadIdx.x;   // 256 threads, 8 blocks
    int B = blockIdx.x;
    short* w16 = (short*)(wsf + OFF_U16);

    if (B == 0) {
        if (t < 16) {
            const sv8 zz = {0,0,0,0,0,0,0,0};
            h[(size_t)32*BG_CH + t] = zz;
        }
        if (t < DWC) {
            float bb1 = b1[t], bb4 = b4[t];
            for (int c = 0; c < CH; ++c) {
                bb1 = fmaf(w1[t*CH + c], ln1b[c], bb1);
                bb4 = fmaf(w4[t*CH + c], ln2b[c], bb4);
            }
            wsf[OFF_PB1 + t] = bb1;
            wsf[OFF_PB4 + t] = bb4;
        }
        if (t < CH) {
            wsf[OFF_PB35 + 4*t + 0] = b3[t];
            wsf[OFF_PB35 + 4*t + 1] = beta[t];
            wsf[OFF_PB35 + 4*t + 2] = gamma[t];
            wsf[OFF_PB35 + 4*t + 3] = b5[t];
        }
        for (int idx = t; idx < 27*DWC; idx += 256) {   // mod_w transpose [27][128]
            int k = idx >> 7, c = idx & 127;
            wsf[OFF_MODWT + idx] = mod_w[c*27 + k];
        }
    }
    {   // s*demod: 32 outputs per block, 8 threads per output
        int o   = B*32 + (t >> 3);
        int sub = t & 7;
        int b = o >> 7, ch = o & 127;
        const float4* s4 = (const float4*)(style + b*SDIM) + sub*16;
        const float4* wv = (const float4*)(style_w + ch*SDIM) + sub*16;
        float s0=0.f, s1=0.f, s2=0.f, s3=0.f;
        #pragma unroll
        for (int i = 0; i < 16; ++i) {
            float4 a_ = s4[i], b_ = wv[i];
            s0 = fmaf(a_.x, b_.x, s0); s1 = fmaf(a_.y, b_.y, s1);
            s2 = fmaf(a_.z, b_.z, s2); s3 = fmaf(a_.w, b_.w, s3);
        }
        float ps = (s0 + s1) + (s2 + s3);
        ps += __shfl_xor(ps, 1); ps += __shfl_xor(ps, 2); ps += __shfl_xor(ps, 4);
        if (sub == 0) {
            float s = style_b[ch] + ps;
            float k2 = 0.f;
            for (int j = 0; j < 27; ++j) { float w = mod_w[ch*27 + j]; k2 = fmaf(w, w, k2); }
            wsf[OFF_SMOD + o]   = s * rsqrtf(fmaf(k2, s*s, 1e-8f));
            wsf[OFF_POOLED + o] = 0.f;
        }
    }
    for (int idx = B*1024 + t; idx < B*1024 + 1024; idx += 256) {  // W1F / W4F
        int m = idx >> 6, k = idx & 63;
        int dst = (((k >> 3)*DWC + m) << 3) + (k & 7);
        w16[U16_W1F + dst] = f2bs(w1[idx] * ln1w[k]);
        w16[U16_W4F + dst] = f2bs(w4[idx] * ln2w[k]);
    }
    for (int idx = B*1024 + t; idx < B*1024 + 1024; idx += 256) {  // W5F
        int m = idx >> 7, k = idx & 127;
        w16[U16_W5F + (((k >> 3)*CH + m) << 3) + (k & 7)] = f2bs(w5[idx]);
    }
}

// ---------------- K1: LN1 + pw1 (MFMA) -> h padded layout ----------------
// One 16-voxel job per wave; W1F staged in LDS (round-8 tail recipe).
__global__ __launch_bounds__(256) void lnpw1_kernel(const float* __restrict__ inp,
                                                    const float* __restrict__ wsf,
                                                    sv8* __restrict__ h) {
    __shared__ sv8  w1s[1024];            // 16 KB
    __shared__ short ht[4*2176];          // 17 KB transpose
    int tid  = threadIdx.x;
    int blk  = blockIdx.x;
    int wid  = tid >> 6;
    int lane = tid & 63;
    int col  = lane & 15, grp = lane >> 4;
    int b    = blk >> 12;
    int row  = blk & 4095;                 // row within batch (d*64+hy)
    int vx   = (row << 6) + (wid << 4) + col;

    const float* b1p = wsf + OFF_PB1;
    short* hw = ht + wid*2176;

    // ---- issue inp loads first, then stage W1F behind them ----
    const float* xp = inp + (size_t)b * CH * SPATIAL + vx;
    float xv[16];
    #pragma unroll
    for (int e = 0; e < 16; ++e) {
        int k = ((e >> 3) << 5) + (grp << 3) + (e & 7);
        xv[e] = xp[(size_t)k * SPATIAL];
    }
    {
        const sv8* src = (const sv8*)((const short*)(wsf + OFF_U16) + U16_W1F);
        #pragma unroll
        for (int i = 0; i < 4; ++i) w1s[i*256 + tid] = src[i*256 + tid];
    }
    __syncthreads();

    float sum = 0.f, ssq = 0.f;
    #pragma unroll
    for (int e = 0; e < 16; ++e) { sum += xv[e]; ssq = fmaf(xv[e], xv[e], ssq); }
    sum += __shfl_xor(sum, 16); sum += __shfl_xor(sum, 32);
    ssq += __shfl_xor(ssq, 16); ssq += __shfl_xor(ssq, 32);
    float m   = sum * (1.f/64.f);
    float var = fmaxf((ssq - 64.f*m*m) * (1.f/63.f), 0.f);
    float inv = 1.f / (sqrtf(var) + 1e-6f);

    sv8 xb0, xb1;
    #pragma unroll
    for (int i = 0; i < 8; ++i) {
        xb0[i] = f2bs((xv[i]     - m) * inv);
        xb1[i] = f2bs((xv[8 + i] - m) * inv);
    }

    f32x4 acc[8] = {};
    #pragma unroll
    for (int mt = 0; mt < 8; ++mt) {
        acc[mt] = __builtin_amdgcn_mfma_f32_16x16x32_bf16(w1s[(grp    )*DWC + mt*16 + col], xb0, acc[mt], 0, 0, 0);
        acc[mt] = __builtin_amdgcn_mfma_f32_16x16x32_bf16(w1s[(grp + 4)*DWC + mt*16 + col], xb1, acc[mt], 0, 0, 0);
    }

    // epilogue + transpose to [v][8ch] chunks
    #pragma unroll
    for (int mt = 0; mt < 8; ++mt) {
        sv4 p;
        #pragma unroll
        for (int r = 0; r < 4; ++r) {
            int f = mt*16 + 4*grp + r;
            p[r] = f2bs(acc[mt][r] + b1p[f]);
        }
        *(sv4*)(hw + col*136 + mt*16 + 4*grp) = p;
    }
    #pragma unroll
    for (int gq = 0; gq < 4; ++gq) {
        int g = gq*4 + grp;
        sv8 vrow = *(const sv8*)(hw + col*136 + g*8);
        size_t base = (size_t)(b*16 + g) * BG_CH + row*ROWS;
        h[base + 1 + (wid << 4) + col] = vrow;
        if (wid == 0 && col == 0) {       // zero this row's pad chunk
            const sv8 zz = {0,0,0,0,0,0,0,0};
            h[base] = zz;
        }
    }
}

// ---------------- K2: depthwise 3x3x3 + mod + GELU -> a, pooled ---------
// packed-f32 (fv2) math: v_pk_fma_f32 does 2 FMAs per issue slot.
__global__ __launch_bounds__(256) void conv_kernel(const sv8* __restrict__ h,
                                                   const float* __restrict__ mod_b,
                                                   const float* __restrict__ wsf,
                                                   sv8* __restrict__ a,
                                                   float* __restrict__ pooled) {
    __shared__ float part[4][8];
    int tid = threadIdx.x;
    int w   = tid & 63;
    int dq  = tid >> 6;
    int hy  = blockIdx.x & 63;
    int bg  = blockIdx.x >> 6;
    int g   = bg & 15;
    int b   = bg >> 4;

    const sv8* hP  = h + (size_t)bg * BG_CH;
    sv8*      adst = a + (size_t)bg * SPATIAL;
    const float* mwt = wsf + OFF_MODWT + g*8;
    const float* smp = wsf + OFF_SMOD + b*DWC + g*8;
    const float* mbp = mod_b + g*8;

    bool r0ok = (hy > 0), r2ok = (hy < 63);
    int d0 = dq << 4;

    fv2 an[4] = {}, am[4] = {}, ao[4] = {};
    fv2 psum[4] = {};

    #pragma unroll 1
    for (int i = 0; i < 18; ++i) {
        int dd = d0 - 1 + i;
        fv2 f[9][4];
        if ((unsigned)dd < 64u) {
            const sv8* p = hP + dd*PLANE_CH + hy*ROWS + 1 + w;
            sv8 cv[9];
            const sv8 zz = {0,0,0,0,0,0,0,0};
            if (r0ok) { cv[0] = p[-ROWS-1]; cv[1] = p[-ROWS]; cv[2] = p[-ROWS+1]; }
            else      { cv[0] = zz; cv[1] = zz; cv[2] = zz; }
            cv[3] = p[-1]; cv[4] = p[0]; cv[5] = p[1];
            if (r2ok) { cv[6] = p[ROWS-1]; cv[7] = p[ROWS]; cv[8] = p[ROWS+1]; }
            else      { cv[6] = zz; cv[7] = zz; cv[8] = zz; }
            #pragma unroll
            for (int r = 0; r < 9; ++r) {
                uv4 u = __builtin_bit_cast(uv4, cv[r]);
                #pragma unroll
                for (int c4 = 0; c4 < 4; ++c4) {
                    fv2 fr;
                    fr.x = __uint_as_float(u[c4] << 16);
                    fr.y = __uint_as_float(u[c4] & 0xFFFF0000u);
                    f[r][c4] = fr;
                }
            }
        } else {
            #pragma unroll
            for (int r = 0; r < 9; ++r)
                #pragma unroll
                for (int c4 = 0; c4 < 4; ++c4) f[r][c4] = (fv2)(0.f);
        }

        if (i >= 2) {
            #pragma unroll
            for (int r = 0; r < 9; ++r) {
                const fv2* wr = (const fv2*)(mwt + (18 + r)*DWC);
                #pragma unroll
                for (int c4 = 0; c4 < 4; ++c4) ao[c4] = wr[c4]*f[r][c4] + ao[c4];
            }
            int o = d0 + i - 2;
            sv8 ov;
            #pragma unroll
            for (int c4 = 0; c4 < 4; ++c4) {
                float v0 = gelu_f(fmaf(ao[c4].x, smp[2*c4],     mbp[2*c4]));
                float v1 = gelu_f(fmaf(ao[c4].y, smp[2*c4 + 1], mbp[2*c4 + 1]));
                psum[c4].x += v0; psum[c4].y += v1;
                ov[2*c4]     = f2bs(v0);
                ov[2*c4 + 1] = f2bs(v1);
            }
            adst[o*4096 + hy*64 + w] = ov;
        }
        if (i >= 1 && i <= 16) {
            #pragma unroll
            for (int r = 0; r < 9; ++r) {
                const fv2* wr = (const fv2*)(mwt + (9 + r)*DWC);
                #pragma unroll
                for (int c4 = 0; c4 < 4; ++c4) am[c4] = wr[c4]*f[r][c4] + am[c4];
            }
        }
        if (i <= 15) {
            #pragma unroll
            for (int c4 = 0; c4 < 4; ++c4) an[c4] = (fv2)(0.f);
            #pragma unroll
            for (int r = 0; r < 9; ++r) {
                const fv2* wr = (const fv2*)(mwt + r*DWC);
                #pragma unroll
                for (int c4 = 0; c4 < 4; ++c4) an[c4] = wr[c4]*f[r][c4] + an[c4];
            }
        }
        #pragma unroll
        for (int c4 = 0; c4 < 4; ++c4) { ao[c4] = am[c4]; am[c4] = an[c4]; }
    }

    #pragma unroll
    for (int c = 0; c < 8; ++c) {
        float s = (c & 1) ? psum[c >> 1].y : psum[c >> 1].x;
        #pragma unroll
        for (int off = 32; off > 0; off >>= 1) s += __shfl_xor(s, off);
        if ((tid & 63) == 0) part[dq][c] = s;
    }
    __syncthreads();
    if (tid < 8)
        atomicAdd(&pooled[b*DWC + g*8 + tid],
                  part[0][tid] + part[1][tid] + part[2][tid] + part[3][tid]);
}

// ---------------- K3: SCA gate + fold into W3F (bf16 frags) -------------
__global__ void gate_kernel(const float* __restrict__ sca_w,
                            const float* __restrict__ sca_b,
                            const float* __restrict__ w3,
                            float* __restrict__ wsf) {
    __shared__ float gsh[256];
    int t = threadIdx.x;                  // 256, 8 blocks
    int b = t >> 7, o = t & 127;
    const float invS = 1.f / (float)SPATIAL;
    float gval = sca_b[o];
    for (int i = 0; i < DWC; ++i)
        gval = fmaf(sca_w[o*DWC + i], wsf[OFF_POOLED + b*DWC + i] * invS, gval);
    gsh[t] = gval;
    __syncthreads();
    int e = blockIdx.x * 256 + t;         // 0..2047 sv8 frags
    int bb = e >> 10, kf = (e >> 6) & 15, m = e & 63;
    sv8 frag;
    #pragma unroll
    for (int i = 0; i < 8; ++i) {
        int k = kf*8 + i;
        frag[i] = f2bs(w3[m*DWC + k] * gsh[bb*DWC + k]);
    }
    sv8* w3f = (sv8*)((short*)(wsf + OFF_U16) + U16_W3F);
    w3f[e] = frag;
}

// ---------------- K4: pw3 + residual + LN2 + pw4 + GELU + pw5 (MFMA) ----
// Round-10 exact: 1 job/wave, 8192 blocks, W3 staged in LDS (separate
// buffers, single barrier), NO setprio. Measured 141 us.
__global__ __launch_bounds__(256) void tail_kernel(const float* __restrict__ inp,
                                                   const sv8* __restrict__ a,
                                                   const float* __restrict__ wsf,
                                                   float* __restrict__ out) {
    __shared__ sv8  w3s[1024];            // 16 KB
    __shared__ short yt[4][2176];         // 17 KB transpose
    int tid  = threadIdx.x;
    int wid  = tid >> 6;
    int lane = tid & 63;
    int col  = lane & 15, grp = lane >> 4;
    int blk  = blockIdx.x;
    int b    = blk >> 12;
    int vx   = ((blk & 4095) << 6) + (wid << 4) + col;

    const short* w16 = (const short*)(wsf + OFF_U16);
    const sv8* W4 = (const sv8*)(w16 + U16_W4F);
    const sv8* W5 = (const sv8*)(w16 + U16_W5F);
    const float*  b4p  = wsf + OFF_PB4;
    const float4* pb35 = (const float4*)(wsf + OFF_PB35);
    short* yw = &yt[wid][0];

    // ---- issue HBM loads first (a-chunks + inp), then stage W3 ----
    sv8 bq[4];
    #pragma unroll
    for (int ks = 0; ks < 4; ++ks)
        bq[ks] = a[(size_t)(b*16 + ks*4 + grp) * SPATIAL + vx];
    float xin[16];
    #pragma unroll
    for (int j = 0; j < 16; ++j) {
        int c = (j >> 2)*16 + 4*grp + (j & 3);
        xin[j] = inp[((size_t)(b*CH + c)) * SPATIAL + vx];
    }
    {
        const sv8* src = (const sv8*)(w16 + U16_W3F) + (size_t)b * 1024;
        #pragma unroll
        for (int i = 0; i < 4; ++i) w3s[i*256 + tid] = src[i*256 + tid];
    }
    __syncthreads();

    // ---- pw3 (W3 from LDS) ----
    f32x4 acc3[4] = {};
    #pragma unroll
    for (int mt = 0; mt < 4; ++mt)
        #pragma unroll
        for (int ks = 0; ks < 4; ++ks)
            acc3[mt] = __builtin_amdgcn_mfma_f32_16x16x32_bf16(
                w3s[(ks*4 + grp)*64 + mt*16 + col], bq[ks], acc3[mt], 0, 0, 0);

    // ---- residual + LN2 stats ----
    float y[16];
    float sum = 0.f, ssq = 0.f;
    #pragma unroll
    for (int mt = 0; mt < 4; ++mt)
        #pragma unroll
        for (int r = 0; r < 4; ++r) {
            int c = mt*16 + 4*grp + r;
            float4 pb = pb35[c];
            float tt = acc3[mt][r] + pb.x;
            float yv = fmaf(tt, pb.y, xin[mt*4 + r]);
            y[mt*4 + r] = yv; sum += yv; ssq = fmaf(yv, yv, ssq);
        }
    sum += __shfl_xor(sum, 16); sum += __shfl_xor(sum, 32);
    ssq += __shfl_xor(ssq, 16); ssq += __shfl_xor(ssq, 32);
    float m2   = sum * (1.f/64.f);
    float var2 = fmaxf((ssq - 64.f*m2*m2) * (1.f/63.f), 0.f);
    float inv2 = 1.f / (sqrtf(var2) + 1e-6f);

    // ---- normalized y -> bf16 B-frags via LDS transpose ----
    #pragma unroll
    for (int mt = 0; mt < 4; ++mt) {
        sv4 p;
        #pragma unroll
        for (int r = 0; r < 4; ++r)
            p[r] = f2bs((y[mt*4 + r] - m2) * inv2);
        *(sv4*)(yw + col*136 + mt*16 + 4*grp) = p;
    }
    sv8 by0 = *(const sv8*)(yw + col*136 + grp*8);
    sv8 by1 = *(const sv8*)(yw + col*136 + grp*8 + 32);

    // ---- pw4 ----
    f32x4 acc4[8] = {};
    #pragma unroll
    for (int mt = 0; mt < 8; ++mt) {
        acc4[mt] = __builtin_amdgcn_mfma_f32_16x16x32_bf16(W4[(grp    )*DWC + mt*16 + col], by0, acc4[mt], 0, 0, 0);
        acc4[mt] = __builtin_amdgcn_mfma_f32_16x16x32_bf16(W4[(grp + 4)*DWC + mt*16 + col], by1, acc4[mt], 0, 0, 0);
    }

    // ---- gelu -> bf16 B-frags ----
    #pragma unroll
    for (int mt = 0; mt < 8; ++mt) {
        sv4 p;
        #pragma unroll
        for (int r = 0; r < 4; ++r) {
            int f = mt*16 + 4*grp + r;
            p[r] = f2bs(gelu_f(acc4[mt][r] + b4p[f]));
        }
        *(sv4*)(yw + col*136 + mt*16 + 4*grp) = p;
    }
    sv8 bg[4];
    #pragma unroll
    for (int ks = 0; ks < 4; ++ks)
        bg[ks] = *(const sv8*)(yw + col*136 + grp*8 + ks*32);

    // ---- pw5 ----
    f32x4 acc5[4] = {};
    #pragma unroll
    for (int mt = 0; mt < 4; ++mt)
        #pragma unroll
        for (int ks = 0; ks < 4; ++ks)
            acc5[mt] = __builtin_amdgcn_mfma_f32_16x16x32_bf16(
                W5[(ks*4 + grp)*64 + mt*16 + col], bg[ks], acc5[mt], 0, 0, 0);

    #pragma unroll
    for (int mt = 0; mt < 4; ++mt)
        #pragma unroll
        for (int r = 0; r < 4; ++r) {
            int c = mt*16 + 4*grp + r;
            float4 pb = pb35[c];
            float o = fmaf(acc5[mt][r] + pb.w, pb.z, y[mt*4 + r]);
            out[((size_t)(b*CH + c)) * SPATIAL + vx] = o;
        }
}

// ---------------- host launcher -----------------------------------------
extern "C" void kernel_launch(void* const* d_in, const int* in_sizes, int n_in,
                              void* d_out, int out_size, void* d_ws, size_t ws_size,
                              hipStream_t stream) {
    const float* inp     = (const float*)d_in[0];
    const float* style   = (const float*)d_in[1];
    const float* w1      = (const float*)d_in[2];
    const float* b1      = (const float*)d_in[3];
    const float* mod_w   = (const float*)d_in[4];
    const float* mod_b   = (const float*)d_in[5];
    const float* style_w = (const float*)d_in[6];
    const float* style_b = (const float*)d_in[7];
    const float* sca_w   = (const float*)d_in[8];
    const float* sca_b   = (const float*)d_in[9];
    const float* w3      = (const float*)d_in[10];
    const float* b3      = (const float*)d_in[11];
    const float* w4      = (const float*)d_in[12];
    const float* b4      = (const float*)d_in[13];
    const float* w5      = (const float*)d_in[14];
    const float* b5      = (const float*)d_in[15];
    const float* ln1w    = (const float*)d_in[16];
    const float* ln1b    = (const float*)d_in[17];
    const float* ln2w    = (const float*)d_in[18];
    const float* ln2b    = (const float*)d_in[19];
    const float* beta    = (const float*)d_in[20];
    const float* gamma   = (const float*)d_in[21];

    sv8*   h   = (sv8*)d_ws;
    sv8*   a   = (sv8*)((char*)d_ws + HPAD_BYTES);
    float* wsf = (float*)((char*)d_ws + HPAD_BYTES + A_BYTES);
    float* out = (float*)d_out;

    prep_kernel<<<8, 256, 0, stream>>>(style, w1, b1, mod_w, style_w, style_b,
                                       b3, w4, b4, w5, b5,
                                       ln1w, ln1b, ln2w, ln2b, beta, gamma, wsf, h);
    lnpw1_kernel<<<8192, 256, 0, stream>>>(inp, wsf, h);
    conv_kernel<<<2048, 256, 0, stream>>>(h, mod_b, wsf, a, wsf + OFF_POOLED);
    gate_kernel<<<8, 256, 0, stream>>>(sca_w, sca_b, w3, wsf);
    tail_kernel<<<8192, 256, 0, stream>>>(inp, a, wsf, out);
}